// Round 7
// baseline (163.036 us; speedup 1.0000x reference)
//
#include <hip/hip_runtime.h>

// EntityLinker forward, MI355X/gfx950.
// R7: split kernels. el_gather (grid 2048, tiny LDS, 8 blocks/CU resident)
// writes pre-swizzled c_h/q_h + bf16 qsum half-sums to ws; el_compute
// (grid 1024, LDS 40960) stages 32KB linearly and runs R5's proven P3-P6.
// Tiers: bf16-table gather (ws>=59.8M) / f32-direct gather (ws>=34.2M) /
// R5 monolith f32 fallback.

typedef __attribute__((ext_vector_type(8))) short     short8;
typedef __attribute__((ext_vector_type(8))) __bf16    bf16x8;
typedef __attribute__((ext_vector_type(4))) float     f32x4;
typedef __attribute__((ext_vector_type(4))) int       int4v;

#define SWZ8(row, off) ((off) ^ (((row) & 7) << 4))
#define SWZQ(row, off) ((off) ^ (((row) & 7) << 4) ^ ((((row) >> 3) & 3) << 5))

// ---- el_compute / fallback LDS: 40960 B ----
#define CH_OFF  0        // c_h [64][128] bf16, 256B rows, SWZ8
#define QH_OFF  16384    // q_h [64][128] bf16, 256B rows, SWZQ -> wq after P4
#define X_OFF   32768    // att [64][64] bf16 SWZ8 / out partials / (fallback: qsum partials)
#define LDS_SIZE 40960

__device__ __forceinline__ unsigned short f2bf(float x) {
    __bf16 h = (__bf16)x;
    return __builtin_bit_cast(unsigned short, h);
}
__device__ __forceinline__ float bf2f(unsigned short u) {
    return __builtin_bit_cast(float, ((unsigned)u) << 16);
}
__device__ __forceinline__ float bflo(unsigned u) {
    return __builtin_bit_cast(float, u << 16);
}
__device__ __forceinline__ float bfhi(unsigned u) {
    return __builtin_bit_cast(float, u & 0xFFFF0000u);
}
__device__ __forceinline__ unsigned pk2(float a, float b) {
    return (unsigned)f2bf(a) | ((unsigned)f2bf(b) << 16);
}
__device__ __forceinline__ f32x4 mfma16(short8 a, short8 b, f32x4 c) {
    return __builtin_amdgcn_mfma_f32_16x16x32_bf16(
        __builtin_bit_cast(bf16x8, a), __builtin_bit_cast(bf16x8, b), c, 0, 0, 0);
}

// W_h [640][128] f32 -> whT [128][640] bf16.
__global__ __launch_bounds__(256) void el_prep(const float* __restrict__ W_h,
                                               unsigned short* __restrict__ whT) {
    int t = blockIdx.x * 256 + threadIdx.x;
    int k = t >> 7, n = t & 127;
    whT[n * 640 + k] = f2bf(W_h[t]);
}

// embed f32 [100000][128] -> bf16 table in ws.
__global__ __launch_bounds__(256) void el_conv(const float* __restrict__ e,
                                               unsigned short* __restrict__ ebf) {
    long i = ((long)blockIdx.x * 256 + threadIdx.x) * 8;
    f32x4 a = *(const f32x4*)(e + i);
    f32x4 c = *(const f32x4*)(e + i + 4);
    uint4 pk;
    pk.x = pk2(a[0], a[1]); pk.y = pk2(a[2], a[3]);
    pk.z = pk2(c[0], c[1]); pk.w = pk2(c[2], c[3]);
    *(uint4*)(ebf + i) = pk;
}

// ---- gather: one block per (b, half). 32 cols + 32 q rows each. ----
template <bool BF16E>
__global__ __launch_bounds__(256, 8) void el_gather(
    const int* __restrict__ q_ids, const int* __restrict__ c_ids,
    const int* __restrict__ num_qs, const float* __restrict__ emb,
    const unsigned short* __restrict__ ebf,
    unsigned short* __restrict__ chqh,      // [1024] x 32768B (pre-swizzled)
    unsigned short* __restrict__ qsh)       // [1024][2][128] bf16 half-sums
{
    __shared__ __align__(16) char smem[3328]; // idc 1024 | idq 128 | qsp 2048
    const int tid = threadIdx.x;
    const int hb = blockIdx.x, b = hb >> 1, half = hb & 1;
    const int nq = num_qs[b] > 0 ? num_qs[b] : 1;
    char* bch = (char*)chqh + (size_t)b * 32768;
    int* idc = (int*)smem;                  // 256 ints
    int* idq = (int*)(smem + 1024);         // 32 ints
    float* qsp = (float*)(smem + 1280);     // [4][128] f32

    if (tid < 256) idc[tid] = c_ids[(b << 9) + (half << 8) + tid];
    if (tid < 32)  idq[tid] = q_ids[(b << 6) + (half << 5) + tid];
    __syncthreads();

    const int l4 = tid & 15, gg = tid >> 4;   // 16 groups of 16 lanes
    // c-gather: 2 cols per group
    #pragma unroll
    for (int cc = 0; cc < 2; ++cc) {
        const int cl = gg + cc * 16;           // 0..31
        const int c = (half << 5) + cl;
        const int* idp = idc + cl * 8;
        int id8[8];
        #pragma unroll
        for (int t = 0; t < 8; ++t) id8[t] = idp[t];
        int cnt = 0;
        #pragma unroll
        for (int t = 0; t < 8; ++t) cnt += (id8[t] != 0);
        float acc[8] = {0.f,0.f,0.f,0.f,0.f,0.f,0.f,0.f};
        #pragma unroll
        for (int t = 0; t < 8; ++t) {
            if constexpr (BF16E) {
                uint4 v = *(const uint4*)(ebf + (long)id8[t] * 128 + l4 * 8);
                acc[0] += bflo(v.x); acc[1] += bfhi(v.x);
                acc[2] += bflo(v.y); acc[3] += bfhi(v.y);
                acc[4] += bflo(v.z); acc[5] += bfhi(v.z);
                acc[6] += bflo(v.w); acc[7] += bfhi(v.w);
            } else {
                f32x4 lo = *(const f32x4*)(emb + (long)id8[t] * 128 + l4 * 8);
                f32x4 hi = *(const f32x4*)(emb + (long)id8[t] * 128 + l4 * 8 + 4);
                acc[0] += lo[0]; acc[1] += lo[1]; acc[2] += lo[2]; acc[3] += lo[3];
                acc[4] += hi[0]; acc[5] += hi[1]; acc[6] += hi[2]; acc[7] += hi[3];
            }
        }
        float inv = 1.0f / (float)(cnt > 0 ? cnt : 1);
        uint4 pk;
        pk.x = pk2(acc[0]*inv, acc[1]*inv); pk.y = pk2(acc[2]*inv, acc[3]*inv);
        pk.z = pk2(acc[4]*inv, acc[5]*inv); pk.w = pk2(acc[6]*inv, acc[7]*inv);
        *(uint4*)(bch + SWZ8(c, c * 256 + l4 * 16)) = pk;
    }
    // q-gather: 2 rows per group + masked partial sums
    float qa[8] = {0.f,0.f,0.f,0.f,0.f,0.f,0.f,0.f};
    #pragma unroll
    for (int qq = 0; qq < 2; ++qq) {
        const int ql = gg + (qq << 4);
        const int q = (half << 5) + ql;
        int id = idq[ql];
        uint4 v;
        float e8[8];
        if constexpr (BF16E) {
            v = *(const uint4*)(ebf + (long)id * 128 + l4 * 8);
            e8[0]=bflo(v.x); e8[1]=bfhi(v.x); e8[2]=bflo(v.y); e8[3]=bfhi(v.y);
            e8[4]=bflo(v.z); e8[5]=bfhi(v.z); e8[6]=bflo(v.w); e8[7]=bfhi(v.w);
        } else {
            f32x4 lo = *(const f32x4*)(emb + (long)id * 128 + l4 * 8);
            f32x4 hi = *(const f32x4*)(emb + (long)id * 128 + l4 * 8 + 4);
            e8[0]=lo[0]; e8[1]=lo[1]; e8[2]=lo[2]; e8[3]=lo[3];
            e8[4]=hi[0]; e8[5]=hi[1]; e8[6]=hi[2]; e8[7]=hi[3];
            v.x = pk2(lo[0], lo[1]); v.y = pk2(lo[2], lo[3]);
            v.z = pk2(hi[0], hi[1]); v.w = pk2(hi[2], hi[3]);
        }
        *(uint4*)(bch + 16384 + SWZQ(q, q * 256 + l4 * 16)) = v;
        if (q < nq)
            #pragma unroll
            for (int e = 0; e < 8; ++e) qa[e] += e8[e];
    }
    #pragma unroll
    for (int e = 0; e < 8; ++e) {
        qa[e] += __shfl_xor(qa[e], 16);
        qa[e] += __shfl_xor(qa[e], 32);
    }
    const int lane = tid & 63, w = tid >> 6;
    if (lane < 16) {
        *(f32x4*)(qsp + w * 128 + lane * 8)     = (f32x4){qa[0],qa[1],qa[2],qa[3]};
        *(f32x4*)(qsp + w * 128 + lane * 8 + 4) = (f32x4){qa[4],qa[5],qa[6],qa[7]};
    }
    __syncthreads();
    if (tid < 128) {
        float s = qsp[tid] + qsp[128 + tid] + qsp[256 + tid] + qsp[384 + tid];
        qsh[((b << 1) + half) * 128 + tid] = f2bf(s);   // half-sum, no div
    }
}

// ---- compute: R5's P3-P6 on staged LDS image ----
__global__ __launch_bounds__(256, 4) void el_compute(
    const int* __restrict__ num_qs,
    const unsigned short* __restrict__ chqh,
    const unsigned short* __restrict__ whT,
    const unsigned short* __restrict__ qsh,
    const float* __restrict__ b_h,
    const float* __restrict__ W_o, const float* __restrict__ b_o,
    float* __restrict__ out)
{
    __shared__ __align__(16) char smem[LDS_SIZE];
    const int tid = threadIdx.x;
    const int b = blockIdx.x;
    const int nq = num_qs[b] > 0 ? num_qs[b] : 1;

    // ---- stage 32KB (pre-swizzled) ----
    {
        const uint4* src = (const uint4*)((const char*)chqh + (size_t)b * 32768);
        uint4* dst = (uint4*)smem;
        #pragma unroll
        for (int i = 0; i < 8; ++i) dst[tid + i * 256] = src[tid + i * 256];
    }
    __syncthreads();

    const int lane = tid & 63, w = tid >> 6;
    const int lr = lane & 15, lg = lane >> 4;

    // ---- P3: sim + in-reg softmax -> att in X ----
    {
        short8 a[4];
        const int arow = w * 16 + lr;
        #pragma unroll
        for (int s = 0; s < 4; ++s)
            a[s] = *(const short8*)(smem + CH_OFF + SWZ8(arow, arow * 256 + s * 64 + lg * 16));
        f32x4 sim[4];
        #pragma unroll
        for (int ct = 0; ct < 4; ++ct) {
            f32x4 acc = {0.f, 0.f, 0.f, 0.f};
            const int q = ct * 16 + lr;
            #pragma unroll
            for (int s = 0; s < 4; ++s) {
                short8 bf = *(const short8*)(smem + QH_OFF + SWZQ(q, q * 256 + s * 64 + lg * 16));
                acc = mfma16(a[s], bf, acc);
            }
            sim[ct] = acc;
        }
        const float scale = 0.08838834764831845f;  // 1/sqrt(128)
        #pragma unroll
        for (int ct = 0; ct < 4; ++ct) {
            const int q = ct * 16 + lr;
            #pragma unroll
            for (int r = 0; r < 4; ++r)
                sim[ct][r] = (q < nq) ? sim[ct][r] * scale : -3.0e38f;
        }
        float mx[4], sm[4];
        #pragma unroll
        for (int r = 0; r < 4; ++r)
            mx[r] = fmaxf(fmaxf(sim[0][r], sim[1][r]), fmaxf(sim[2][r], sim[3][r]));
        #pragma unroll
        for (int off = 1; off <= 8; off <<= 1)
            #pragma unroll
            for (int r = 0; r < 4; ++r)
                mx[r] = fmaxf(mx[r], __shfl_xor(mx[r], off));
        #pragma unroll
        for (int ct = 0; ct < 4; ++ct)
            #pragma unroll
            for (int r = 0; r < 4; ++r)
                sim[ct][r] = __expf(sim[ct][r] - mx[r]);
        #pragma unroll
        for (int r = 0; r < 4; ++r)
            sm[r] = (sim[0][r] + sim[1][r]) + (sim[2][r] + sim[3][r]);
        #pragma unroll
        for (int off = 1; off <= 8; off <<= 1)
            #pragma unroll
            for (int r = 0; r < 4; ++r)
                sm[r] += __shfl_xor(sm[r], off);
        const int cbase = w * 16 + lg * 4;
        #pragma unroll
        for (int ct = 0; ct < 4; ++ct)
            #pragma unroll
            for (int r = 0; r < 4; ++r) {
                int c = cbase + r, q = ct * 16 + lr;
                *(unsigned short*)(smem + X_OFF + SWZ8(c, c * 128 + q * 2)) =
                    f2bf(sim[ct][r] * (1.0f / sm[r]));
            }
    }
    __syncthreads();

    // ---- P4: weighted_q = att @ q_h ----
    f32x4 wqa[8];
    {
        short8 pa[2];
        const int arow = w * 16 + lr;
        #pragma unroll
        for (int s = 0; s < 2; ++s)
            pa[s] = *(const short8*)(smem + X_OFF + SWZ8(arow, arow * 128 + s * 64 + lg * 16));
        #pragma unroll
        for (int ct = 0; ct < 8; ++ct) {
            f32x4 acc = {0.f, 0.f, 0.f, 0.f};
            const int d = ct * 16 + lr;
            const int dlx = (d << 1) ^ (lg << 5);
            #pragma unroll
            for (int s = 0; s < 2; ++s) {
                const int qbase = (s << 5) + (lg << 3);
                short8 bf;
                #pragma unroll
                for (int j = 0; j < 8; ++j) {
                    int off = QH_OFF + ((qbase + j) << 8) + (dlx ^ (j << 4));
                    bf[j] = *(const short*)(smem + off);
                }
                acc = mfma16(pa[s], bf, acc);
            }
            wqa[ct] = acc;
        }
    }
    __syncthreads();
    {
        const int cbase = w * 16 + lg * 4;
        #pragma unroll
        for (int ct = 0; ct < 8; ++ct)
            #pragma unroll
            for (int r = 0; r < 4; ++r) {
                int c = cbase + r, d = ct * 16 + lr;
                *(unsigned short*)(smem + QH_OFF + SWZQ(c, c * 256 + d * 2)) =
                    f2bf(wqa[ct][r]);
            }
    }
    __syncthreads();

    // ---- P5: column-split GEMM + tanh + W_o ----
    {
        f32x4 acc[4][2];
        #pragma unroll
        for (int rt = 0; rt < 4; ++rt) {
            acc[rt][0] = (f32x4){0.f, 0.f, 0.f, 0.f};
            acc[rt][1] = (f32x4){0.f, 0.f, 0.f, 0.f};
        }
        const int n0 = w * 32 + lr, n1 = n0 + 16;
        const int klane = lg * 8;
        // qsum from half-sums, in-register
        short8 qsf[4];
        {
            const unsigned short* qh = qsh + (size_t)b * 256;
            const float invq = 1.0f / (float)nq;
            #pragma unroll
            for (int sk = 0; sk < 4; ++sk) {
                short8 h0 = *(const short8*)(qh + sk * 32 + klane);
                short8 h1 = *(const short8*)(qh + 128 + sk * 32 + klane);
                short8 r;
                #pragma unroll
                for (int e = 0; e < 8; ++e)
                    r[e] = (short)f2bf((bf2f((unsigned short)h0[e]) +
                                        bf2f((unsigned short)h1[e])) * invq);
                qsf[sk] = r;
            }
        }
        const float bh0 = b_h[n0], bh1 = b_h[n1];
        const float wo0 = W_o[n0], wo1 = W_o[n1];

        for (int sk = 0; sk < 4; ++sk) {
            short8 B0[5], B1[5];
            #pragma unroll
            for (int p = 0; p < 5; ++p) {
                B0[p] = *(const short8*)(whT + n0 * 640 + p * 128 + sk * 32 + klane);
                B1[p] = *(const short8*)(whT + n1 * 640 + p * 128 + sk * 32 + klane);
            }
            #pragma unroll
            for (int rt = 0; rt < 4; ++rt) {
                const int row = rt * 16 + lr;
                short8 chf = *(const short8*)(smem + CH_OFF + SWZ8(row, row * 256 + sk * 64 + lg * 16));
                short8 wqf = *(const short8*)(smem + QH_OFF + SWZQ(row, row * 256 + sk * 64 + lg * 16));
                short8 prf, adf;
                #pragma unroll
                for (int e = 0; e < 8; ++e) {
                    float cv = bf2f((unsigned short)chf[e]);
                    float wv = bf2f((unsigned short)wqf[e]);
                    prf[e] = (short)f2bf(cv * wv);
                    adf[e] = (short)f2bf(fabsf(cv - wv));
                }
                acc[rt][0] = mfma16(qsf[sk], B0[0], acc[rt][0]);
                acc[rt][1] = mfma16(qsf[sk], B1[0], acc[rt][1]);
                acc[rt][0] = mfma16(chf,     B0[1], acc[rt][0]);
                acc[rt][1] = mfma16(chf,     B1[1], acc[rt][1]);
                acc[rt][0] = mfma16(wqf,     B0[2], acc[rt][0]);
                acc[rt][1] = mfma16(wqf,     B1[2], acc[rt][1]);
                acc[rt][0] = mfma16(prf,     B0[3], acc[rt][0]);
                acc[rt][1] = mfma16(prf,     B1[3], acc[rt][1]);
                acc[rt][0] = mfma16(adf,     B0[4], acc[rt][0]);
                acc[rt][1] = mfma16(adf,     B1[4], acc[rt][1]);
            }
        }

        #pragma unroll
        for (int rt = 0; rt < 4; ++rt)
            #pragma unroll
            for (int r = 0; r < 4; ++r) {
                float x0 = acc[rt][0][r] + bh0;
                float x1 = acc[rt][1][r] + bh1;
                float t0 = 1.0f - 2.0f / (__expf(2.0f * x0) + 1.0f);  // tanh
                float t1 = 1.0f - 2.0f / (__expf(2.0f * x1) + 1.0f);
                float po = t0 * wo0 + t1 * wo1;
                #pragma unroll
                for (int off = 1; off <= 8; off <<= 1)
                    po += __shfl_xor(po, off);
                if (lr == 0)
                    *(float*)(smem + X_OFF + (w * 64 + rt * 16 + lg * 4 + r) * 4) = po;
            }
    }
    __syncthreads();

    // ---- P6: combine wave partials ----
    if (tid < 64) {
        float o = b_o[0];
        #pragma unroll
        for (int w2 = 0; w2 < 4; ++w2)
            o += *(const float*)(smem + X_OFF + (w2 * 64 + tid) * 4);
        out[(b << 6) + tid] = o;
    }
}

// ---- fallback: R5 monolith, f32 gather ----
__global__ __launch_bounds__(256, 4) void el_mono(
    const int* __restrict__ q_ids, const int* __restrict__ c_ids,
    const int* __restrict__ num_qs, const float* __restrict__ emb,
    const unsigned short* __restrict__ whT,
    unsigned short* __restrict__ qsum_ws,
    const float* __restrict__ b_h,
    const float* __restrict__ W_o, const float* __restrict__ b_o,
    float* __restrict__ out)
{
    __shared__ __align__(16) char smem[LDS_SIZE];
    const int tid = threadIdx.x;
    const int b = blockIdx.x;
    const int nq = num_qs[b] > 0 ? num_qs[b] : 1;

    {
        const int l4 = tid & 15, gg = tid >> 4;
        #pragma unroll 2
        for (int cc = 0; cc < 4; ++cc) {
            const int c = gg + cc * 16;
            const int* idp = c_ids + (((b << 6) + c) << 3);
            int4v i0 = *(const int4v*)idp, i1 = *(const int4v*)(idp + 4);
            int id8[8] = {i0[0], i0[1], i0[2], i0[3], i1[0], i1[1], i1[2], i1[3]};
            int cnt = 0;
            #pragma unroll
            for (int t = 0; t < 8; ++t) cnt += (id8[t] != 0);
            float acc[8] = {0.f,0.f,0.f,0.f,0.f,0.f,0.f,0.f};
            #pragma unroll
            for (int t = 0; t < 8; ++t) {
                f32x4 lo = *(const f32x4*)(emb + (long)id8[t] * 128 + l4 * 8);
                f32x4 hi = *(const f32x4*)(emb + (long)id8[t] * 128 + l4 * 8 + 4);
                acc[0] += lo[0]; acc[1] += lo[1]; acc[2] += lo[2]; acc[3] += lo[3];
                acc[4] += hi[0]; acc[5] += hi[1]; acc[6] += hi[2]; acc[7] += hi[3];
            }
            float inv = 1.0f / (float)(cnt > 0 ? cnt : 1);
            uint4 pk;
            pk.x = pk2(acc[0]*inv, acc[1]*inv); pk.y = pk2(acc[2]*inv, acc[3]*inv);
            pk.z = pk2(acc[4]*inv, acc[5]*inv); pk.w = pk2(acc[6]*inv, acc[7]*inv);
            *(uint4*)(smem + CH_OFF + SWZ8(c, c * 256 + l4 * 16)) = pk;
        }
        float qa[8] = {0.f,0.f,0.f,0.f,0.f,0.f,0.f,0.f};
        #pragma unroll
        for (int qq = 0; qq < 4; ++qq) {
            const int q = gg + (qq << 4);
            int id = q_ids[(b << 6) + q];
            f32x4 lo = *(const f32x4*)(emb + (long)id * 128 + l4 * 8);
            f32x4 hi = *(const f32x4*)(emb + (long)id * 128 + l4 * 8 + 4);
            uint4 v;
            v.x = pk2(lo[0], lo[1]); v.y = pk2(lo[2], lo[3]);
            v.z = pk2(hi[0], hi[1]); v.w = pk2(hi[2], hi[3]);
            *(uint4*)(smem + QH_OFF + SWZQ(q, q * 256 + l4 * 16)) = v;
            if (q < nq) {
                qa[0] += lo[0]; qa[1] += lo[1]; qa[2] += lo[2]; qa[3] += lo[3];
                qa[4] += hi[0]; qa[5] += hi[1]; qa[6] += hi[2]; qa[7] += hi[3];
            }
        }
        float* qsp = (float*)(smem + X_OFF);
        *(f32x4*)(qsp + gg * 128 + l4 * 8)     = (f32x4){qa[0], qa[1], qa[2], qa[3]};
        *(f32x4*)(qsp + gg * 128 + l4 * 8 + 4) = (f32x4){qa[4], qa[5], qa[6], qa[7]};
    }
    __syncthreads();

    if (tid < 128) {
        const float* qsp = (const float*)(smem + X_OFF);
        float s = 0.f;
        #pragma unroll
        for (int g = 0; g < 16; ++g) s += qsp[g * 128 + tid];
        qsum_ws[(b << 7) + tid] = f2bf(s / (float)nq);
    }
    __syncthreads();

    const int lane = tid & 63, w = tid >> 6;
    const int lr = lane & 15, lg = lane >> 4;

    {
        short8 a[4];
        const int arow = w * 16 + lr;
        #pragma unroll
        for (int s = 0; s < 4; ++s)
            a[s] = *(const short8*)(smem + CH_OFF + SWZ8(arow, arow * 256 + s * 64 + lg * 16));
        f32x4 sim[4];
        #pragma unroll
        for (int ct = 0; ct < 4; ++ct) {
            f32x4 acc = {0.f, 0.f, 0.f, 0.f};
            const int q = ct * 16 + lr;
            #pragma unroll
            for (int s = 0; s < 4; ++s) {
                short8 bf = *(const short8*)(smem + QH_OFF + SWZQ(q, q * 256 + s * 64 + lg * 16));
                acc = mfma16(a[s], bf, acc);
            }
            sim[ct] = acc;
        }
        const float scale = 0.08838834764831845f;
        #pragma unroll
        for (int ct = 0; ct < 4; ++ct) {
            const int q = ct * 16 + lr;
            #pragma unroll
            for (int r = 0; r < 4; ++r)
                sim[ct][r] = (q < nq) ? sim[ct][r] * scale : -3.0e38f;
        }
        float mx[4], sm[4];
        #pragma unroll
        for (int r = 0; r < 4; ++r)
            mx[r] = fmaxf(fmaxf(sim[0][r], sim[1][r]), fmaxf(sim[2][r], sim[3][r]));
        #pragma unroll
        for (int off = 1; off <= 8; off <<= 1)
            #pragma unroll
            for (int r = 0; r < 4; ++r)
                mx[r] = fmaxf(mx[r], __shfl_xor(mx[r], off));
        #pragma unroll
        for (int ct = 0; ct < 4; ++ct)
            #pragma unroll
            for (int r = 0; r < 4; ++r)
                sim[ct][r] = __expf(sim[ct][r] - mx[r]);
        #pragma unroll
        for (int r = 0; r < 4; ++r)
            sm[r] = (sim[0][r] + sim[1][r]) + (sim[2][r] + sim[3][r]);
        #pragma unroll
        for (int off = 1; off <= 8; off <<= 1)
            #pragma unroll
            for (int r = 0; r < 4; ++r)
                sm[r] += __shfl_xor(sm[r], off);
        const int cbase = w * 16 + lg * 4;
        #pragma unroll
        for (int ct = 0; ct < 4; ++ct)
            #pragma unroll
            for (int r = 0; r < 4; ++r) {
                int c = cbase + r, q = ct * 16 + lr;
                *(unsigned short*)(smem + X_OFF + SWZ8(c, c * 128 + q * 2)) =
                    f2bf(sim[ct][r] * (1.0f / sm[r]));
            }
    }
    __syncthreads();

    f32x4 wqa[8];
    {
        short8 pa[2];
        const int arow = w * 16 + lr;
        #pragma unroll
        for (int s = 0; s < 2; ++s)
            pa[s] = *(const short8*)(smem + X_OFF + SWZ8(arow, arow * 128 + s * 64 + lg * 16));
        #pragma unroll
        for (int ct = 0; ct < 8; ++ct) {
            f32x4 acc = {0.f, 0.f, 0.f, 0.f};
            const int d = ct * 16 + lr;
            const int dlx = (d << 1) ^ (lg << 5);
            #pragma unroll
            for (int s = 0; s < 2; ++s) {
                const int qbase = (s << 5) + (lg << 3);
                short8 bf;
                #pragma unroll
                for (int j = 0; j < 8; ++j) {
                    int off = QH_OFF + ((qbase + j) << 8) + (dlx ^ (j << 4));
                    bf[j] = *(const short*)(smem + off);
                }
                acc = mfma16(pa[s], bf, acc);
            }
            wqa[ct] = acc;
        }
    }
    __syncthreads();
    {
        const int cbase = w * 16 + lg * 4;
        #pragma unroll
        for (int ct = 0; ct < 8; ++ct)
            #pragma unroll
            for (int r = 0; r < 4; ++r) {
                int c = cbase + r, d = ct * 16 + lr;
                *(unsigned short*)(smem + QH_OFF + SWZQ(c, c * 256 + d * 2)) =
                    f2bf(wqa[ct][r]);
            }
    }
    __syncthreads();

    {
        f32x4 acc[4][2];
        #pragma unroll
        for (int rt = 0; rt < 4; ++rt) {
            acc[rt][0] = (f32x4){0.f, 0.f, 0.f, 0.f};
            acc[rt][1] = (f32x4){0.f, 0.f, 0.f, 0.f};
        }
        const int n0 = w * 32 + lr, n1 = n0 + 16;
        const int klane = lg * 8;
        short8 qsf[4];
        #pragma unroll
        for (int sk = 0; sk < 4; ++sk)
            qsf[sk] = *(const short8*)(qsum_ws + (b << 7) + sk * 32 + klane);
        const float bh0 = b_h[n0], bh1 = b_h[n1];
        const float wo0 = W_o[n0], wo1 = W_o[n1];

        for (int sk = 0; sk < 4; ++sk) {
            short8 B0[5], B1[5];
            #pragma unroll
            for (int p = 0; p < 5; ++p) {
                B0[p] = *(const short8*)(whT + n0 * 640 + p * 128 + sk * 32 + klane);
                B1[p] = *(const short8*)(whT + n1 * 640 + p * 128 + sk * 32 + klane);
            }
            #pragma unroll
            for (int rt = 0; rt < 4; ++rt) {
                const int row = rt * 16 + lr;
                short8 chf = *(const short8*)(smem + CH_OFF + SWZ8(row, row * 256 + sk * 64 + lg * 16));
                short8 wqf = *(const short8*)(smem + QH_OFF + SWZQ(row, row * 256 + sk * 64 + lg * 16));
                short8 prf, adf;
                #pragma unroll
                for (int e = 0; e < 8; ++e) {
                    float cv = bf2f((unsigned short)chf[e]);
                    float wv = bf2f((unsigned short)wqf[e]);
                    prf[e] = (short)f2bf(cv * wv);
                    adf[e] = (short)f2bf(fabsf(cv - wv));
                }
                acc[rt][0] = mfma16(qsf[sk], B0[0], acc[rt][0]);
                acc[rt][1] = mfma16(qsf[sk], B1[0], acc[rt][1]);
                acc[rt][0] = mfma16(chf,     B0[1], acc[rt][0]);
                acc[rt][1] = mfma16(chf,     B1[1], acc[rt][1]);
                acc[rt][0] = mfma16(wqf,     B0[2], acc[rt][0]);
                acc[rt][1] = mfma16(wqf,     B1[2], acc[rt][1]);
                acc[rt][0] = mfma16(prf,     B0[3], acc[rt][0]);
                acc[rt][1] = mfma16(prf,     B1[3], acc[rt][1]);
                acc[rt][0] = mfma16(adf,     B0[4], acc[rt][0]);
                acc[rt][1] = mfma16(adf,     B1[4], acc[rt][1]);
            }
        }

        #pragma unroll
        for (int rt = 0; rt < 4; ++rt)
            #pragma unroll
            for (int r = 0; r < 4; ++r) {
                float x0 = acc[rt][0][r] + bh0;
                float x1 = acc[rt][1][r] + bh1;
                float t0 = 1.0f - 2.0f / (__expf(2.0f * x0) + 1.0f);
                float t1 = 1.0f - 2.0f / (__expf(2.0f * x1) + 1.0f);
                float po = t0 * wo0 + t1 * wo1;
                #pragma unroll
                for (int off = 1; off <= 8; off <<= 1)
                    po += __shfl_xor(po, off);
                if (lr == 0)
                    *(float*)(smem + X_OFF + (w * 64 + rt * 16 + lg * 4 + r) * 4) = po;
            }
    }
    __syncthreads();

    if (tid < 64) {
        float o = b_o[0];
        #pragma unroll
        for (int w2 = 0; w2 < 4; ++w2)
            o += *(const float*)(smem + X_OFF + (w2 * 64 + tid) * 4);
        out[(b << 6) + tid] = o;
    }
}

extern "C" void kernel_launch(void* const* d_in, const int* in_sizes, int n_in,
                              void* d_out, int out_size, void* d_ws, size_t ws_size,
                              hipStream_t stream) {
    const int*   q_ids  = (const int*)d_in[0];
    const int*   c_ids  = (const int*)d_in[1];
    const int*   num_qs = (const int*)d_in[2];
    // d_in[3] num_cols: unused by the reference forward
    const float* embed  = (const float*)d_in[4];
    const float* W_h    = (const float*)d_in[5];
    const float* b_h    = (const float*)d_in[6];
    const float* W_o    = (const float*)d_in[7];
    const float* b_o    = (const float*)d_in[8];
    float*       out    = (float*)d_out;

    // ws: whT 160K | qsh 512K | chqh 32M | ebf 25.6M
    const size_t QSH_OFF  = 163840;
    const size_t CHQH_OFF = QSH_OFF + 524288;                  //    688,128
    const size_t CHQH_END = CHQH_OFF + (size_t)1024 * 32768;   // 34,242,560
    const size_t EBF_END  = CHQH_END + (size_t)100000 * 256;   // 59,842,560
    unsigned short* whT  = (unsigned short*)d_ws;
    unsigned short* qsh  = (unsigned short*)((char*)d_ws + QSH_OFF);
    unsigned short* chqh = (unsigned short*)((char*)d_ws + CHQH_OFF);
    unsigned short* ebf  = (unsigned short*)((char*)d_ws + CHQH_END);

    el_prep<<<320, 256, 0, stream>>>(W_h, whT);

    if (ws_size >= EBF_END) {
        el_conv<<<6250, 256, 0, stream>>>(embed, ebf);
        el_gather<true><<<2048, 256, 0, stream>>>(q_ids, c_ids, num_qs, embed,
                                                  ebf, chqh, qsh);
        el_compute<<<1024, 256, 0, stream>>>(num_qs, chqh, whT, qsh,
                                             b_h, W_o, b_o, out);
    } else if (ws_size >= CHQH_END) {
        el_gather<false><<<2048, 256, 0, stream>>>(q_ids, c_ids, num_qs, embed,
                                                   ebf, chqh, qsh);
        el_compute<<<1024, 256, 0, stream>>>(num_qs, chqh, whT, qsh,
                                             b_h, W_o, b_o, out);
    } else {
        el_mono<<<1024, 256, 0, stream>>>(q_ids, c_ids, num_qs, embed, whT,
                                          qsh, b_h, W_o, b_o, out);
    }
}

// Round 8
// 161.922 us; speedup vs baseline: 1.0069x; 1.0069x over previous
//
#include <hip/hip_runtime.h>

// EntityLinker forward, MI355X/gfx950.
// R8: half-batch blocks. grid 2048 = (b, c-half); each block: 32 c-cols +
// all 64 q rows. P3 on waves 0-1 while wave 2 reduces qsum in LDS; P4 on
// all 4 waves; P5 rt-halved. LDS 30976B. No inter-kernel feature round-trip
// (R7 regression) and no qsum global bounce. Numerics identical to R5.

typedef __attribute__((ext_vector_type(8))) short     short8;
typedef __attribute__((ext_vector_type(8))) __bf16    bf16x8;
typedef __attribute__((ext_vector_type(4))) float     f32x4;
typedef __attribute__((ext_vector_type(4))) int       int4v;

#define SWZ8(row, off) ((off) ^ (((row) & 7) << 4))
#define SWZQ(row, off) ((off) ^ (((row) & 7) << 4) ^ ((((row) >> 3) & 3) << 5))

// ---- LDS layout (bytes), total 30976 ----
#define H_CH   0        // c_h [32][128] bf16, 256B rows, SWZ8          (8K)
#define H_QH   8192     // q_h [64][128] bf16, 256B rows, SWZQ -> wq[32] (16K)
#define H_X    24576    // att [32][64] bf16 128B rows SWZ8 -> outp [4][32] f32 (4K)
#define H_QSP  28672    // qsum wave partials [4][128] f32               (2K)
#define H_QS   30720    // qsum bf16 [128]                               (256B)
#define H_LDS  30976

__device__ __forceinline__ unsigned short f2bf(float x) {
    __bf16 h = (__bf16)x;
    return __builtin_bit_cast(unsigned short, h);
}
__device__ __forceinline__ float bf2f(unsigned short u) {
    return __builtin_bit_cast(float, ((unsigned)u) << 16);
}
__device__ __forceinline__ float bflo(unsigned u) {
    return __builtin_bit_cast(float, u << 16);
}
__device__ __forceinline__ float bfhi(unsigned u) {
    return __builtin_bit_cast(float, u & 0xFFFF0000u);
}
__device__ __forceinline__ unsigned pk2(float a, float b) {
    return (unsigned)f2bf(a) | ((unsigned)f2bf(b) << 16);
}
__device__ __forceinline__ f32x4 mfma16(short8 a, short8 b, f32x4 c) {
    return __builtin_amdgcn_mfma_f32_16x16x32_bf16(
        __builtin_bit_cast(bf16x8, a), __builtin_bit_cast(bf16x8, b), c, 0, 0, 0);
}

// W_h [640][128] f32 -> whT [128][640] bf16.
__global__ __launch_bounds__(256) void el_prep(const float* __restrict__ W_h,
                                               unsigned short* __restrict__ whT) {
    int t = blockIdx.x * 256 + threadIdx.x;
    int k = t >> 7, n = t & 127;
    whT[n * 640 + k] = f2bf(W_h[t]);
}

// embed f32 [100000][128] -> bf16 table in ws.
__global__ __launch_bounds__(256) void el_conv(const float* __restrict__ e,
                                               unsigned short* __restrict__ ebf) {
    long i = ((long)blockIdx.x * 256 + threadIdx.x) * 8;
    f32x4 a = *(const f32x4*)(e + i);
    f32x4 c = *(const f32x4*)(e + i + 4);
    uint4 pk;
    pk.x = pk2(a[0], a[1]); pk.y = pk2(a[2], a[3]);
    pk.z = pk2(c[0], c[1]); pk.w = pk2(c[2], c[3]);
    *(uint4*)(ebf + i) = pk;
}

template <bool BF16E>
__global__ __launch_bounds__(256, 4) void el_half(
    const int* __restrict__ q_ids, const int* __restrict__ c_ids,
    const int* __restrict__ num_qs, const float* __restrict__ emb,
    const unsigned short* __restrict__ ebf,
    const unsigned short* __restrict__ whT,
    const float* __restrict__ b_h,
    const float* __restrict__ W_o, const float* __restrict__ b_o,
    float* __restrict__ out)
{
    __shared__ __align__(16) char smem[H_LDS];
    const int tid = threadIdx.x;
    const int hb = blockIdx.x, b = hb >> 1, half = hb & 1;
    const int nq = num_qs[b] > 0 ? num_qs[b] : 1;
    float* qsp = (float*)(smem + H_QSP);
    unsigned short* qs = (unsigned short*)(smem + H_QS);

    // ---------------- P1: gathers ----------------
    {
        const int l4 = tid & 15, gg = tid >> 4;       // 16 groups of 16 lanes
        // ids first (break id->row chain early)
        const int cg = (b << 6) + (half << 5) + gg;   // global col of local gg
        int4v ci[2][2];
        ci[0][0] = *(const int4v*)(c_ids + (cg << 3));
        ci[0][1] = *(const int4v*)(c_ids + (cg << 3) + 4);
        ci[1][0] = *(const int4v*)(c_ids + ((cg + 16) << 3));
        ci[1][1] = *(const int4v*)(c_ids + ((cg + 16) << 3) + 4);
        int qid[4];
        #pragma unroll
        for (int qq = 0; qq < 4; ++qq)
            qid[qq] = q_ids[(b << 6) + gg + (qq << 4)];

        // c-gather: 2 local cols per group (cl = gg, gg+16)
        #pragma unroll
        for (int cc = 0; cc < 2; ++cc) {
            const int cl = gg + cc * 16;              // local row 0..31
            int id8[8] = {ci[cc][0][0], ci[cc][0][1], ci[cc][0][2], ci[cc][0][3],
                          ci[cc][1][0], ci[cc][1][1], ci[cc][1][2], ci[cc][1][3]};
            int cnt = 0;
            #pragma unroll
            for (int t = 0; t < 8; ++t) cnt += (id8[t] != 0);
            float acc[8] = {0.f,0.f,0.f,0.f,0.f,0.f,0.f,0.f};
            #pragma unroll
            for (int t = 0; t < 8; ++t) {
                if constexpr (BF16E) {
                    uint4 v = *(const uint4*)(ebf + (long)id8[t] * 128 + l4 * 8);
                    acc[0] += bflo(v.x); acc[1] += bfhi(v.x);
                    acc[2] += bflo(v.y); acc[3] += bfhi(v.y);
                    acc[4] += bflo(v.z); acc[5] += bfhi(v.z);
                    acc[6] += bflo(v.w); acc[7] += bfhi(v.w);
                } else {
                    f32x4 lo = *(const f32x4*)(emb + (long)id8[t] * 128 + l4 * 8);
                    f32x4 hi = *(const f32x4*)(emb + (long)id8[t] * 128 + l4 * 8 + 4);
                    acc[0] += lo[0]; acc[1] += lo[1]; acc[2] += lo[2]; acc[3] += lo[3];
                    acc[4] += hi[0]; acc[5] += hi[1]; acc[6] += hi[2]; acc[7] += hi[3];
                }
            }
            float inv = 1.0f / (float)(cnt > 0 ? cnt : 1);
            uint4 pk;
            pk.x = pk2(acc[0]*inv, acc[1]*inv); pk.y = pk2(acc[2]*inv, acc[3]*inv);
            pk.z = pk2(acc[4]*inv, acc[5]*inv); pk.w = pk2(acc[6]*inv, acc[7]*inv);
            *(uint4*)(smem + H_CH + SWZ8(cl, cl * 256 + l4 * 16)) = pk;
        }
        // q-gather: 4 rows per group (all 64 q) + masked partial sums
        float qa[8] = {0.f,0.f,0.f,0.f,0.f,0.f,0.f,0.f};
        #pragma unroll
        for (int qq = 0; qq < 4; ++qq) {
            const int q = gg + (qq << 4);
            uint4 v;
            float e8[8];
            if constexpr (BF16E) {
                v = *(const uint4*)(ebf + (long)qid[qq] * 128 + l4 * 8);
                e8[0]=bflo(v.x); e8[1]=bfhi(v.x); e8[2]=bflo(v.y); e8[3]=bfhi(v.y);
                e8[4]=bflo(v.z); e8[5]=bfhi(v.z); e8[6]=bflo(v.w); e8[7]=bfhi(v.w);
            } else {
                f32x4 lo = *(const f32x4*)(emb + (long)qid[qq] * 128 + l4 * 8);
                f32x4 hi = *(const f32x4*)(emb + (long)qid[qq] * 128 + l4 * 8 + 4);
                e8[0]=lo[0]; e8[1]=lo[1]; e8[2]=lo[2]; e8[3]=lo[3];
                e8[4]=hi[0]; e8[5]=hi[1]; e8[6]=hi[2]; e8[7]=hi[3];
                v.x = pk2(lo[0], lo[1]); v.y = pk2(lo[2], lo[3]);
                v.z = pk2(hi[0], hi[1]); v.w = pk2(hi[2], hi[3]);
            }
            *(uint4*)(smem + H_QH + SWZQ(q, q * 256 + l4 * 16)) = v;
            if (q < nq)
                #pragma unroll
                for (int e = 0; e < 8; ++e) qa[e] += e8[e];
        }
        // combine the wave's 4 groups in-register, one wave-partial per wave
        #pragma unroll
        for (int e = 0; e < 8; ++e) {
            qa[e] += __shfl_xor(qa[e], 16);
            qa[e] += __shfl_xor(qa[e], 32);
        }
        const int lane = tid & 63, w = tid >> 6;
        if (lane < 16) {
            *(f32x4*)(qsp + w * 128 + lane * 8)     = (f32x4){qa[0],qa[1],qa[2],qa[3]};
            *(f32x4*)(qsp + w * 128 + lane * 8 + 4) = (f32x4){qa[4],qa[5],qa[6],qa[7]};
        }
    }
    __syncthreads();

    const int lane = tid & 63, w = tid >> 6;
    const int lr = lane & 15, lg = lane >> 4;

    // ---------------- P3 (waves 0-1) || qsum reduce (wave 2) ----------------
    if (w < 2) {
        short8 a[4];
        const int arow = w * 16 + lr;                 // c-local 0..31
        #pragma unroll
        for (int s = 0; s < 4; ++s)
            a[s] = *(const short8*)(smem + H_CH + SWZ8(arow, arow * 256 + s * 64 + lg * 16));
        f32x4 sim[4];
        #pragma unroll
        for (int ct = 0; ct < 4; ++ct) {
            f32x4 acc = {0.f, 0.f, 0.f, 0.f};
            const int q = ct * 16 + lr;
            #pragma unroll
            for (int s = 0; s < 4; ++s) {
                short8 bf = *(const short8*)(smem + H_QH + SWZQ(q, q * 256 + s * 64 + lg * 16));
                acc = mfma16(a[s], bf, acc);
            }
            sim[ct] = acc;
        }
        const float scale = 0.08838834764831845f;  // 1/sqrt(128)
        #pragma unroll
        for (int ct = 0; ct < 4; ++ct) {
            const int q = ct * 16 + lr;
            #pragma unroll
            for (int r = 0; r < 4; ++r)
                sim[ct][r] = (q < nq) ? sim[ct][r] * scale : -3.0e38f;
        }
        float mx[4], sm[4];
        #pragma unroll
        for (int r = 0; r < 4; ++r)
            mx[r] = fmaxf(fmaxf(sim[0][r], sim[1][r]), fmaxf(sim[2][r], sim[3][r]));
        #pragma unroll
        for (int off = 1; off <= 8; off <<= 1)
            #pragma unroll
            for (int r = 0; r < 4; ++r)
                mx[r] = fmaxf(mx[r], __shfl_xor(mx[r], off));
        #pragma unroll
        for (int ct = 0; ct < 4; ++ct)
            #pragma unroll
            for (int r = 0; r < 4; ++r)
                sim[ct][r] = __expf(sim[ct][r] - mx[r]);
        #pragma unroll
        for (int r = 0; r < 4; ++r)
            sm[r] = (sim[0][r] + sim[1][r]) + (sim[2][r] + sim[3][r]);
        #pragma unroll
        for (int off = 1; off <= 8; off <<= 1)
            #pragma unroll
            for (int r = 0; r < 4; ++r)
                sm[r] += __shfl_xor(sm[r], off);
        const int cbase = w * 16 + lg * 4;
        #pragma unroll
        for (int ct = 0; ct < 4; ++ct)
            #pragma unroll
            for (int r = 0; r < 4; ++r) {
                int c = cbase + r, q = ct * 16 + lr;
                *(unsigned short*)(smem + H_X + SWZ8(c, c * 128 + q * 2)) =
                    f2bf(sim[ct][r] * (1.0f / sm[r]));
            }
    } else if (w == 2) {
        const float invq = 1.0f / (float)nq;
        #pragma unroll
        for (int h = 0; h < 2; ++h) {
            int d = lane + h * 64;
            float s = qsp[d] + qsp[128 + d] + qsp[256 + d] + qsp[384 + d];
            qs[d] = f2bf(s * invq);
        }
    }
    __syncthreads();

    // ---------------- P4: weighted_q = att @ q_h (all 4 waves) ----------------
    f32x4 wqa[4];
    const int ctile = w & 1, ct0 = (w >> 1) * 4;
    {
        short8 pa[2];
        const int arow = ctile * 16 + lr;
        #pragma unroll
        for (int s = 0; s < 2; ++s)
            pa[s] = *(const short8*)(smem + H_X + SWZ8(arow, arow * 128 + s * 64 + lg * 16));
        #pragma unroll
        for (int ct = 0; ct < 4; ++ct) {
            f32x4 acc = {0.f, 0.f, 0.f, 0.f};
            const int d = (ct0 + ct) * 16 + lr;
            const int dlx = (d << 1) ^ (lg << 5);
            #pragma unroll
            for (int s = 0; s < 2; ++s) {
                const int qbase = (s << 5) + (lg << 3);
                short8 bf;
                #pragma unroll
                for (int j = 0; j < 8; ++j) {
                    int off = H_QH + ((qbase + j) << 8) + (dlx ^ (j << 4));
                    bf[j] = *(const short*)(smem + off);
                }
                acc = mfma16(pa[s], bf, acc);
            }
            wqa[ct] = acc;
        }
    }
    __syncthreads();   // q_h/att reads done -> wq overwrites QH rows 0..31
    {
        const int cbase = ctile * 16 + lg * 4;
        #pragma unroll
        for (int ct = 0; ct < 4; ++ct)
            #pragma unroll
            for (int r = 0; r < 4; ++r) {
                int c = cbase + r, d = (ct0 + ct) * 16 + lr;
                *(unsigned short*)(smem + H_QH + SWZQ(c, c * 256 + d * 2)) =
                    f2bf(wqa[ct][r]);
            }
    }
    __syncthreads();

    // ---------------- P5: column-split GEMM + tanh + W_o ----------------
    {
        f32x4 acc[2][2];
        #pragma unroll
        for (int rt = 0; rt < 2; ++rt) {
            acc[rt][0] = (f32x4){0.f, 0.f, 0.f, 0.f};
            acc[rt][1] = (f32x4){0.f, 0.f, 0.f, 0.f};
        }
        const int n0 = w * 32 + lr, n1 = n0 + 16;
        const int klane = lg * 8;
        short8 qsf[4];
        #pragma unroll
        for (int sk = 0; sk < 4; ++sk)
            qsf[sk] = *(const short8*)(qs + sk * 32 + klane);
        const float bh0 = b_h[n0], bh1 = b_h[n1];
        const float wo0 = W_o[n0], wo1 = W_o[n1];

        for (int sk = 0; sk < 4; ++sk) {
            short8 B0[5], B1[5];
            #pragma unroll
            for (int p = 0; p < 5; ++p) {
                B0[p] = *(const short8*)(whT + n0 * 640 + p * 128 + sk * 32 + klane);
                B1[p] = *(const short8*)(whT + n1 * 640 + p * 128 + sk * 32 + klane);
            }
            #pragma unroll
            for (int rt = 0; rt < 2; ++rt) {
                const int row = rt * 16 + lr;
                short8 chf = *(const short8*)(smem + H_CH + SWZ8(row, row * 256 + sk * 64 + lg * 16));
                short8 wqf = *(const short8*)(smem + H_QH + SWZQ(row, row * 256 + sk * 64 + lg * 16));
                short8 prf, adf;
                #pragma unroll
                for (int e = 0; e < 8; ++e) {
                    float cv = bf2f((unsigned short)chf[e]);
                    float wv = bf2f((unsigned short)wqf[e]);
                    prf[e] = (short)f2bf(cv * wv);
                    adf[e] = (short)f2bf(fabsf(cv - wv));
                }
                acc[rt][0] = mfma16(qsf[sk], B0[0], acc[rt][0]);
                acc[rt][1] = mfma16(qsf[sk], B1[0], acc[rt][1]);
                acc[rt][0] = mfma16(chf,     B0[1], acc[rt][0]);
                acc[rt][1] = mfma16(chf,     B1[1], acc[rt][1]);
                acc[rt][0] = mfma16(wqf,     B0[2], acc[rt][0]);
                acc[rt][1] = mfma16(wqf,     B1[2], acc[rt][1]);
                acc[rt][0] = mfma16(prf,     B0[3], acc[rt][0]);
                acc[rt][1] = mfma16(prf,     B1[3], acc[rt][1]);
                acc[rt][0] = mfma16(adf,     B0[4], acc[rt][0]);
                acc[rt][1] = mfma16(adf,     B1[4], acc[rt][1]);
            }
        }

        #pragma unroll
        for (int rt = 0; rt < 2; ++rt)
            #pragma unroll
            for (int r = 0; r < 4; ++r) {
                float x0 = acc[rt][0][r] + bh0;
                float x1 = acc[rt][1][r] + bh1;
                float t0 = 1.0f - 2.0f / (__expf(2.0f * x0) + 1.0f);  // tanh
                float t1 = 1.0f - 2.0f / (__expf(2.0f * x1) + 1.0f);
                float po = t0 * wo0 + t1 * wo1;
                #pragma unroll
                for (int off = 1; off <= 8; off <<= 1)
                    po += __shfl_xor(po, off);
                if (lr == 0)
                    *(float*)(smem + H_X + (w * 32 + rt * 16 + lg * 4 + r) * 4) = po;
            }
    }
    __syncthreads();

    // ---------------- P6: combine wave partials ----------------
    if (tid < 32) {
        float o = b_o[0];
        #pragma unroll
        for (int w2 = 0; w2 < 4; ++w2)
            o += *(const float*)(smem + H_X + (w2 * 32 + tid) * 4);
        out[(b << 6) + (half << 5) + tid] = o;
    }
}

extern "C" void kernel_launch(void* const* d_in, const int* in_sizes, int n_in,
                              void* d_out, int out_size, void* d_ws, size_t ws_size,
                              hipStream_t stream) {
    const int*   q_ids  = (const int*)d_in[0];
    const int*   c_ids  = (const int*)d_in[1];
    const int*   num_qs = (const int*)d_in[2];
    // d_in[3] num_cols: unused by the reference forward
    const float* embed  = (const float*)d_in[4];
    const float* W_h    = (const float*)d_in[5];
    const float* b_h    = (const float*)d_in[6];
    const float* W_o    = (const float*)d_in[7];
    const float* b_o    = (const float*)d_in[8];
    float*       out    = (float*)d_out;

    // ws: whT [0,163840) | ebf [163840, +25.6M)
    const size_t EBF_OFF = 163840;
    const size_t EBF_END = EBF_OFF + (size_t)100000 * 128 * 2;   // 25,763,840
    unsigned short* whT = (unsigned short*)d_ws;
    unsigned short* ebf = (unsigned short*)((char*)d_ws + EBF_OFF);

    el_prep<<<320, 256, 0, stream>>>(W_h, whT);

    if (ws_size >= EBF_END) {
        el_conv<<<6250, 256, 0, stream>>>(embed, ebf);
        el_half<true><<<2048, 256, 0, stream>>>(q_ids, c_ids, num_qs, embed, ebf,
                                                whT, b_h, W_o, b_o, out);
    } else {
        el_half<false><<<2048, 256, 0, stream>>>(q_ids, c_ids, num_qs, embed, ebf,
                                                 whT, b_h, W_o, b_o, out);
    }
}

// Round 9
// 145.402 us; speedup vs baseline: 1.1213x; 1.1136x over previous
//
#include <hip/hip_runtime.h>

// EntityLinker forward, MI355X/gfx950. One block per batch b, 256 thr (4 waves).
// R9 = R5 structure (best: 52.7us main) + P1 deep-pipelined gather (ids+q
// loads upfront, c-rows in 2-col pairs, 16 loads in flight; launch_bounds
// (256,3) frees VGPR since occupancy is pinned at 3 blocks/CU anyway) +
// prep folded into conv (one launch fewer).

typedef __attribute__((ext_vector_type(8))) short     short8;
typedef __attribute__((ext_vector_type(8))) __bf16    bf16x8;
typedef __attribute__((ext_vector_type(4))) float     f32x4;
typedef __attribute__((ext_vector_type(4))) int       int4v;

#define SWZ8(row, off) ((off) ^ (((row) & 7) << 4))
#define SWZQ(row, off) ((off) ^ (((row) & 7) << 4) ^ ((((row) >> 3) & 3) << 5))

// ---- LDS layout (bytes), total 40960 ----
#define CH_OFF  0        // c_h [64][128] bf16, 256B rows, SWZ8
#define QH_OFF  16384    // q_h [64][128] bf16, 256B rows, SWZQ -> wq after P4
#define X_OFF   32768    // P1-P2: qsum partials [16][128] f32 (8KB)
                         // P3-P4: att [64][64] bf16 SWZ8 ; P5-P6: outp [4][64] f32
#define LDS_SIZE 40960

__device__ __forceinline__ unsigned short f2bf(float x) {
    __bf16 h = (__bf16)x;
    return __builtin_bit_cast(unsigned short, h);
}
__device__ __forceinline__ float bf2f(unsigned short u) {
    return __builtin_bit_cast(float, ((unsigned)u) << 16);
}
__device__ __forceinline__ float bflo(unsigned u) {
    return __builtin_bit_cast(float, u << 16);
}
__device__ __forceinline__ float bfhi(unsigned u) {
    return __builtin_bit_cast(float, u & 0xFFFF0000u);
}
__device__ __forceinline__ unsigned pk2(float a, float b) {
    return (unsigned)f2bf(a) | ((unsigned)f2bf(b) << 16);
}
__device__ __forceinline__ f32x4 mfma16(short8 a, short8 b, f32x4 c) {
    return __builtin_amdgcn_mfma_f32_16x16x32_bf16(
        __builtin_bit_cast(bf16x8, a), __builtin_bit_cast(bf16x8, b), c, 0, 0, 0);
}

// Fused: blocks [0,6250) convert embed f32->bf16; blocks [6250,6570) build
// whT [128][640] bf16 from W_h [640][128] f32.
__global__ __launch_bounds__(256) void el_prepconv(
    const float* __restrict__ e, unsigned short* __restrict__ ebf,
    const float* __restrict__ W_h, unsigned short* __restrict__ whT) {
    if (blockIdx.x < 6250) {
        long i = ((long)blockIdx.x * 256 + threadIdx.x) * 8;
        f32x4 a = *(const f32x4*)(e + i);
        f32x4 c = *(const f32x4*)(e + i + 4);
        uint4 pk;
        pk.x = pk2(a[0], a[1]); pk.y = pk2(a[2], a[3]);
        pk.z = pk2(c[0], c[1]); pk.w = pk2(c[2], c[3]);
        *(uint4*)(ebf + i) = pk;
    } else {
        int t = (blockIdx.x - 6250) * 256 + threadIdx.x;   // 0..81919
        int k = t >> 7, n = t & 127;
        whT[n * 640 + k] = f2bf(W_h[t]);
    }
}

// Standalone prep for the no-ebf fallback tier.
__global__ __launch_bounds__(256) void el_prep(const float* __restrict__ W_h,
                                               unsigned short* __restrict__ whT) {
    int t = blockIdx.x * 256 + threadIdx.x;
    int k = t >> 7, n = t & 127;
    whT[n * 640 + k] = f2bf(W_h[t]);
}

template <bool BF16E>
__global__ __launch_bounds__(256, 3) void el_main(
    const int* __restrict__ q_ids, const int* __restrict__ c_ids,
    const int* __restrict__ num_qs, const float* __restrict__ emb,
    const unsigned short* __restrict__ ebf,
    const unsigned short* __restrict__ whT,
    unsigned short* __restrict__ qsum_ws,
    const float* __restrict__ b_h,
    const float* __restrict__ W_o, const float* __restrict__ b_o,
    float* __restrict__ out)
{
    __shared__ __align__(16) char smem[LDS_SIZE];
    const int tid = threadIdx.x;
    const int b = blockIdx.x;
    const int nq = num_qs[b] > 0 ? num_qs[b] : 1;

    // ---------------- P1: deep-pipelined gathers ----------------
    {
        const int l4 = tid & 15, gg = tid >> 4;       // 16 groups of 16 lanes
        // 1) all ids upfront
        int4v ci[4][2];
        #pragma unroll
        for (int cc = 0; cc < 4; ++cc) {
            const int* idp = c_ids + (((b << 6) + gg + cc * 16) << 3);
            ci[cc][0] = *(const int4v*)idp;
            ci[cc][1] = *(const int4v*)(idp + 4);
        }
        int qid[4];
        #pragma unroll
        for (int qq = 0; qq < 4; ++qq)
            qid[qq] = q_ids[(b << 6) + gg + (qq << 4)];

        if constexpr (BF16E) {
            // 2) q row loads issued first (consumed last)
            uint4 qv[4];
            #pragma unroll
            for (int qq = 0; qq < 4; ++qq)
                qv[qq] = *(const uint4*)(ebf + (long)qid[qq] * 128 + l4 * 8);

            // 3) c rows in column pairs: 16 loads in flight per pair
            #pragma unroll
            for (int cp = 0; cp < 2; ++cp) {
                uint4 v0[8], v1[8];
                int cnt0 = 0, cnt1 = 0;
                #pragma unroll
                for (int t = 0; t < 8; ++t) {
                    int i0 = (t < 4) ? ci[cp*2][0][t] : ci[cp*2][1][t-4];
                    v0[t] = *(const uint4*)(ebf + (long)i0 * 128 + l4 * 8);
                    cnt0 += (i0 != 0);
                }
                #pragma unroll
                for (int t = 0; t < 8; ++t) {
                    int i1 = (t < 4) ? ci[cp*2+1][0][t] : ci[cp*2+1][1][t-4];
                    v1[t] = *(const uint4*)(ebf + (long)i1 * 128 + l4 * 8);
                    cnt1 += (i1 != 0);
                }
                #pragma unroll
                for (int h = 0; h < 2; ++h) {
                    const uint4* v = h ? v1 : v0;
                    const int cnt = h ? cnt1 : cnt0;
                    const int c = gg + (cp * 2 + h) * 16;
                    float acc[8] = {0.f,0.f,0.f,0.f,0.f,0.f,0.f,0.f};
                    #pragma unroll
                    for (int t = 0; t < 8; ++t) {
                        acc[0] += bflo(v[t].x); acc[1] += bfhi(v[t].x);
                        acc[2] += bflo(v[t].y); acc[3] += bfhi(v[t].y);
                        acc[4] += bflo(v[t].z); acc[5] += bfhi(v[t].z);
                        acc[6] += bflo(v[t].w); acc[7] += bfhi(v[t].w);
                    }
                    float inv = 1.0f / (float)(cnt > 0 ? cnt : 1);
                    uint4 pk;
                    pk.x = pk2(acc[0]*inv, acc[1]*inv); pk.y = pk2(acc[2]*inv, acc[3]*inv);
                    pk.z = pk2(acc[4]*inv, acc[5]*inv); pk.w = pk2(acc[6]*inv, acc[7]*inv);
                    *(uint4*)(smem + CH_OFF + SWZ8(c, c * 256 + l4 * 16)) = pk;
                }
            }
            // 4) q rows: store + masked partial sums
            float qa[8] = {0.f,0.f,0.f,0.f,0.f,0.f,0.f,0.f};
            #pragma unroll
            for (int qq = 0; qq < 4; ++qq) {
                const int q = gg + (qq << 4);
                *(uint4*)(smem + QH_OFF + SWZQ(q, q * 256 + l4 * 16)) = qv[qq];
                if (q < nq) {
                    qa[0] += bflo(qv[qq].x); qa[1] += bfhi(qv[qq].x);
                    qa[2] += bflo(qv[qq].y); qa[3] += bfhi(qv[qq].y);
                    qa[4] += bflo(qv[qq].z); qa[5] += bfhi(qv[qq].z);
                    qa[6] += bflo(qv[qq].w); qa[7] += bfhi(qv[qq].w);
                }
            }
            float* qsp = (float*)(smem + X_OFF);
            *(f32x4*)(qsp + gg * 128 + l4 * 8)     = (f32x4){qa[0], qa[1], qa[2], qa[3]};
            *(f32x4*)(qsp + gg * 128 + l4 * 8 + 4) = (f32x4){qa[4], qa[5], qa[6], qa[7]};
        } else {
            // f32 fallback: R5's simpler structure
            #pragma unroll 2
            for (int cc = 0; cc < 4; ++cc) {
                const int c = gg + cc * 16;
                int id8[8] = {ci[cc][0][0], ci[cc][0][1], ci[cc][0][2], ci[cc][0][3],
                              ci[cc][1][0], ci[cc][1][1], ci[cc][1][2], ci[cc][1][3]};
                int cnt = 0;
                #pragma unroll
                for (int t = 0; t < 8; ++t) cnt += (id8[t] != 0);
                float acc[8] = {0.f,0.f,0.f,0.f,0.f,0.f,0.f,0.f};
                #pragma unroll
                for (int t = 0; t < 8; ++t) {
                    f32x4 lo = *(const f32x4*)(emb + (long)id8[t] * 128 + l4 * 8);
                    f32x4 hi = *(const f32x4*)(emb + (long)id8[t] * 128 + l4 * 8 + 4);
                    acc[0] += lo[0]; acc[1] += lo[1]; acc[2] += lo[2]; acc[3] += lo[3];
                    acc[4] += hi[0]; acc[5] += hi[1]; acc[6] += hi[2]; acc[7] += hi[3];
                }
                float inv = 1.0f / (float)(cnt > 0 ? cnt : 1);
                uint4 pk;
                pk.x = pk2(acc[0]*inv, acc[1]*inv); pk.y = pk2(acc[2]*inv, acc[3]*inv);
                pk.z = pk2(acc[4]*inv, acc[5]*inv); pk.w = pk2(acc[6]*inv, acc[7]*inv);
                *(uint4*)(smem + CH_OFF + SWZ8(c, c * 256 + l4 * 16)) = pk;
            }
            float qa[8] = {0.f,0.f,0.f,0.f,0.f,0.f,0.f,0.f};
            #pragma unroll
            for (int qq = 0; qq < 4; ++qq) {
                const int q = gg + (qq << 4);
                f32x4 lo = *(const f32x4*)(emb + (long)qid[qq] * 128 + l4 * 8);
                f32x4 hi = *(const f32x4*)(emb + (long)qid[qq] * 128 + l4 * 8 + 4);
                uint4 v;
                v.x = pk2(lo[0], lo[1]); v.y = pk2(lo[2], lo[3]);
                v.z = pk2(hi[0], hi[1]); v.w = pk2(hi[2], hi[3]);
                *(uint4*)(smem + QH_OFF + SWZQ(q, q * 256 + l4 * 16)) = v;
                if (q < nq) {
                    qa[0] += lo[0]; qa[1] += lo[1]; qa[2] += lo[2]; qa[3] += lo[3];
                    qa[4] += hi[0]; qa[5] += hi[1]; qa[6] += hi[2]; qa[7] += hi[3];
                }
            }
            float* qsp = (float*)(smem + X_OFF);
            *(f32x4*)(qsp + gg * 128 + l4 * 8)     = (f32x4){qa[0], qa[1], qa[2], qa[3]};
            *(f32x4*)(qsp + gg * 128 + l4 * 8 + 4) = (f32x4){qa[4], qa[5], qa[6], qa[7]};
        }
    }
    __syncthreads();

    // ---------------- P2: q_summary -> global ws (bf16) ----------------
    if (tid < 128) {
        const float* qsp = (const float*)(smem + X_OFF);
        float s = 0.f;
        #pragma unroll
        for (int g = 0; g < 16; ++g) s += qsp[g * 128 + tid];
        qsum_ws[(b << 7) + tid] = f2bf(s / (float)nq);
    }
    __syncthreads();

    const int lane = tid & 63, w = tid >> 6;
    const int lr = lane & 15, lg = lane >> 4;

    // ---------------- P3: sim + in-reg softmax -> att in X ----------------
    {
        short8 a[4];
        const int arow = w * 16 + lr;
        #pragma unroll
        for (int s = 0; s < 4; ++s)
            a[s] = *(const short8*)(smem + CH_OFF + SWZ8(arow, arow * 256 + s * 64 + lg * 16));
        f32x4 sim[4];
        #pragma unroll
        for (int ct = 0; ct < 4; ++ct) {
            f32x4 acc = {0.f, 0.f, 0.f, 0.f};
            const int q = ct * 16 + lr;
            #pragma unroll
            for (int s = 0; s < 4; ++s) {
                short8 bf = *(const short8*)(smem + QH_OFF + SWZQ(q, q * 256 + s * 64 + lg * 16));
                acc = mfma16(a[s], bf, acc);
            }
            sim[ct] = acc;
        }
        const float scale = 0.08838834764831845f;  // 1/sqrt(128)
        #pragma unroll
        for (int ct = 0; ct < 4; ++ct) {
            const int q = ct * 16 + lr;
            #pragma unroll
            for (int r = 0; r < 4; ++r)
                sim[ct][r] = (q < nq) ? sim[ct][r] * scale : -3.0e38f;
        }
        float mx[4], sm[4];
        #pragma unroll
        for (int r = 0; r < 4; ++r)
            mx[r] = fmaxf(fmaxf(sim[0][r], sim[1][r]), fmaxf(sim[2][r], sim[3][r]));
        #pragma unroll
        for (int off = 1; off <= 8; off <<= 1)
            #pragma unroll
            for (int r = 0; r < 4; ++r)
                mx[r] = fmaxf(mx[r], __shfl_xor(mx[r], off));
        #pragma unroll
        for (int ct = 0; ct < 4; ++ct)
            #pragma unroll
            for (int r = 0; r < 4; ++r)
                sim[ct][r] = __expf(sim[ct][r] - mx[r]);
        #pragma unroll
        for (int r = 0; r < 4; ++r)
            sm[r] = (sim[0][r] + sim[1][r]) + (sim[2][r] + sim[3][r]);
        #pragma unroll
        for (int off = 1; off <= 8; off <<= 1)
            #pragma unroll
            for (int r = 0; r < 4; ++r)
                sm[r] += __shfl_xor(sm[r], off);
        const int cbase = w * 16 + lg * 4;
        #pragma unroll
        for (int ct = 0; ct < 4; ++ct)
            #pragma unroll
            for (int r = 0; r < 4; ++r) {
                int c = cbase + r, q = ct * 16 + lr;
                *(unsigned short*)(smem + X_OFF + SWZ8(c, c * 128 + q * 2)) =
                    f2bf(sim[ct][r] * (1.0f / sm[r]));
            }
    }
    __syncthreads();

    // ---------------- P4: weighted_q = att @ q_h ----------------
    f32x4 wqa[8];
    {
        short8 pa[2];
        const int arow = w * 16 + lr;
        #pragma unroll
        for (int s = 0; s < 2; ++s)
            pa[s] = *(const short8*)(smem + X_OFF + SWZ8(arow, arow * 128 + s * 64 + lg * 16));
        #pragma unroll
        for (int ct = 0; ct < 8; ++ct) {
            f32x4 acc = {0.f, 0.f, 0.f, 0.f};
            const int d = ct * 16 + lr;
            const int dlx = (d << 1) ^ (lg << 5);
            #pragma unroll
            for (int s = 0; s < 2; ++s) {
                const int qbase = (s << 5) + (lg << 3);
                short8 bf;
                #pragma unroll
                for (int j = 0; j < 8; ++j) {
                    // SWZQ(q, q*256 + d*2), q = qbase+j; (q&7)=j, ((q>>3)&3)=lg
                    int off = QH_OFF + ((qbase + j) << 8) + (dlx ^ (j << 4));
                    bf[j] = *(const short*)(smem + off);
                }
                acc = mfma16(pa[s], bf, acc);
            }
            wqa[ct] = acc;
        }
    }
    __syncthreads();   // q_h/att reads done -> wq overwrites QH
    {
        const int cbase = w * 16 + lg * 4;
        #pragma unroll
        for (int ct = 0; ct < 8; ++ct)
            #pragma unroll
            for (int r = 0; r < 4; ++r) {
                int c = cbase + r, d = ct * 16 + lr;
                *(unsigned short*)(smem + QH_OFF + SWZQ(c, c * 256 + d * 2)) =
                    f2bf(wqa[ct][r]);
            }
    }
    __syncthreads();

    // ---------------- P5: column-split GEMM + tanh + W_o -------------------
    {
        f32x4 acc[4][2];
        #pragma unroll
        for (int rt = 0; rt < 4; ++rt) {
            acc[rt][0] = (f32x4){0.f, 0.f, 0.f, 0.f};
            acc[rt][1] = (f32x4){0.f, 0.f, 0.f, 0.f};
        }
        const int n0 = w * 32 + lr, n1 = n0 + 16;
        const int klane = lg * 8;
        short8 qsf[4];
        #pragma unroll
        for (int sk = 0; sk < 4; ++sk)
            qsf[sk] = *(const short8*)(qsum_ws + (b << 7) + sk * 32 + klane);
        const float bh0 = b_h[n0], bh1 = b_h[n1];
        const float wo0 = W_o[n0], wo1 = W_o[n1];

        for (int sk = 0; sk < 4; ++sk) {
            short8 B0[5], B1[5];
            #pragma unroll
            for (int p = 0; p < 5; ++p) {
                B0[p] = *(const short8*)(whT + n0 * 640 + p * 128 + sk * 32 + klane);
                B1[p] = *(const short8*)(whT + n1 * 640 + p * 128 + sk * 32 + klane);
            }
            #pragma unroll
            for (int rt = 0; rt < 4; ++rt) {
                const int row = rt * 16 + lr;
                short8 chf = *(const short8*)(smem + CH_OFF + SWZ8(row, row * 256 + sk * 64 + lg * 16));
                short8 wqf = *(const short8*)(smem + QH_OFF + SWZQ(row, row * 256 + sk * 64 + lg * 16));
                short8 prf, adf;
                #pragma unroll
                for (int e = 0; e < 8; ++e) {
                    float cv = bf2f((unsigned short)chf[e]);
                    float wv = bf2f((unsigned short)wqf[e]);
                    prf[e] = (short)f2bf(cv * wv);
                    adf[e] = (short)f2bf(fabsf(cv - wv));
                }
                acc[rt][0] = mfma16(qsf[sk], B0[0], acc[rt][0]);
                acc[rt][1] = mfma16(qsf[sk], B1[0], acc[rt][1]);
                acc[rt][0] = mfma16(chf,     B0[1], acc[rt][0]);
                acc[rt][1] = mfma16(chf,     B1[1], acc[rt][1]);
                acc[rt][0] = mfma16(wqf,     B0[2], acc[rt][0]);
                acc[rt][1] = mfma16(wqf,     B1[2], acc[rt][1]);
                acc[rt][0] = mfma16(prf,     B0[3], acc[rt][0]);
                acc[rt][1] = mfma16(prf,     B1[3], acc[rt][1]);
                acc[rt][0] = mfma16(adf,     B0[4], acc[rt][0]);
                acc[rt][1] = mfma16(adf,     B1[4], acc[rt][1]);
            }
        }

        #pragma unroll
        for (int rt = 0; rt < 4; ++rt)
            #pragma unroll
            for (int r = 0; r < 4; ++r) {
                float x0 = acc[rt][0][r] + bh0;
                float x1 = acc[rt][1][r] + bh1;
                float t0 = 1.0f - 2.0f / (__expf(2.0f * x0) + 1.0f);  // tanh
                float t1 = 1.0f - 2.0f / (__expf(2.0f * x1) + 1.0f);
                float po = t0 * wo0 + t1 * wo1;
                #pragma unroll
                for (int off = 1; off <= 8; off <<= 1)
                    po += __shfl_xor(po, off);
                if (lr == 0)
                    *(float*)(smem + X_OFF + (w * 64 + rt * 16 + lg * 4 + r) * 4) = po;
            }
    }
    __syncthreads();

    // ---------------- P6: combine wave partials ----------------
    if (tid < 64) {
        float o = b_o[0];
        #pragma unroll
        for (int w2 = 0; w2 < 4; ++w2)
            o += *(const float*)(smem + X_OFF + (w2 * 64 + tid) * 4);
        out[(b << 6) + tid] = o;
    }
}

extern "C" void kernel_launch(void* const* d_in, const int* in_sizes, int n_in,
                              void* d_out, int out_size, void* d_ws, size_t ws_size,
                              hipStream_t stream) {
    const int*   q_ids  = (const int*)d_in[0];
    const int*   c_ids  = (const int*)d_in[1];
    const int*   num_qs = (const int*)d_in[2];
    // d_in[3] num_cols: unused by the reference forward
    const float* embed  = (const float*)d_in[4];
    const float* W_h    = (const float*)d_in[5];
    const float* b_h    = (const float*)d_in[6];
    const float* W_o    = (const float*)d_in[7];
    const float* b_o    = (const float*)d_in[8];
    float*       out    = (float*)d_out;

    // ws: [0,160K) whT | [160K,416K) qsum bf16 [1024][128] | [416K,+25.6M) ebf
    const size_t EBF_OFF = 425984;
    const size_t EBF_END = EBF_OFF + (size_t)100000 * 128 * 2;   // 26,025,984
    unsigned short* whT  = (unsigned short*)d_ws;
    unsigned short* qsum = (unsigned short*)((char*)d_ws + 163840);
    unsigned short* ebf  = (unsigned short*)((char*)d_ws + EBF_OFF);

    const bool bf16e = ws_size >= EBF_END;
    if (bf16e) {
        el_prepconv<<<6570, 256, 0, stream>>>(embed, ebf, W_h, whT);
        el_main<true><<<1024, 256, 0, stream>>>(q_ids, c_ids, num_qs, embed, ebf,
                                                whT, qsum, b_h, W_o, b_o, out);
    } else {
        el_prep<<<320, 256, 0, stream>>>(W_h, whT);
        el_main<false><<<1024, 256, 0, stream>>>(q_ids, c_ids, num_qs, embed, ebf,
                                                 whT, qsum, b_h, W_o, b_o, out);
    }
}